// Round 10
// baseline (372.850 us; speedup 1.0000x reference)
//
#include <hip/hip_runtime.h>
#include <hip/hip_bf16.h>

typedef __bf16 bf16_t;
typedef __bf16 bf16x8 __attribute__((ext_vector_type(8)));
typedef float  f32x4  __attribute__((ext_vector_type(4)));

#define DK 1024   // d_in  (K)
#define DN 1024   // d_out (N)
#define RNK 32
#define BM 128
#define BN 512
#define BK 64
#define NKT 16

// ---- Pass 1: W_eff = W + C @ V_r^T, bf16, PRE-SWIZZLED ---------------------
// Chunks [bn(2)][kt(16)] of 64KB = LDS image of a 512row x 64k tile:
// byte(rloc,kloc) = rloc*128 + ((kgrp*16) ^ ((rloc&7)<<4)) + (kloc&7)*2,
// kgrp = (kloc>>3). Conflict-free for the GEMM's swizzled ds_read_b128.
__global__ void weff_kernel(const float* __restrict__ W,
                            const float* __restrict__ Vr,
                            const float* __restrict__ C,
                            bf16_t* __restrict__ WeffSw)
{
    const int o  = blockIdx.x;       // 0..1023 (d_out row)
    const int g  = threadIdx.x;      // 0..127  (8-wide d_in group)
    const int d0 = g * 8;

    f32x4 cv[8];
#pragma unroll
    for (int q = 0; q < 8; ++q) cv[q] = *(const f32x4*)(C + o * RNK + q * 4);

    const f32x4* wrow = (const f32x4*)(W + (size_t)o * DK + d0);
    f32x4 w0 = wrow[0], w1 = wrow[1];
    float acc[8];
#pragma unroll
    for (int e = 0; e < 4; ++e) { acc[e] = w0[e]; acc[4 + e] = w1[e]; }

#pragma unroll
    for (int e = 0; e < 8; ++e) {
        const f32x4* vre = (const f32x4*)(Vr + (size_t)(d0 + e) * RNK);
        float s = 0.f;
#pragma unroll
        for (int q = 0; q < 8; ++q) {
            f32x4 v = vre[q];
            s += cv[q][0] * v[0] + cv[q][1] * v[1] + cv[q][2] * v[2] + cv[q][3] * v[3];
        }
        acc[e] += s;
    }

    bf16x8 out;
#pragma unroll
    for (int e = 0; e < 8; ++e) out[e] = (bf16_t)acc[e];

    const int bn = o >> 9, rloc = o & 511;
    const int kt = g >> 3, kgrp = g & 7;
    const size_t byte = (size_t)(bn * 16 + kt) * 65536
                      + rloc * 128 + ((kgrp * 16) ^ ((rloc & 7) << 4));
    *(bf16x8*)((char*)WeffSw + byte) = out;
}

// ---- Pass 2: 128x512 tile, BK=64, 8 waves each 128x64 = 64 MFMA/wave/iter --
// Amortizes the ~2.3k-cyc fixed barrier-phase cost over 2482 cyc of MFMA.
// B: single 64KB LDS buffer; all 8 B-frags prefetched to regs, then a guard
// barrier makes in-place global_load_lds of B(t+1) safe (lands under MFMAs,
// drained by counted vmcnt(4) at iter end). A: dbuf + depth-2 reg prefetch.
__global__ __launch_bounds__(512, 2) void corrlin_gemm_kernel(
    const float* __restrict__ X, const bf16_t* __restrict__ WeffSw,
    const float* __restrict__ bias, float* __restrict__ Out)
{
    __shared__ __align__(16) char smem[98304];
    char* Ab0  = smem;                // 16KB each (128 rows x 64 k bf16)
    char* Ab1  = smem + 16384;
    char* Blds = smem + 32768;        // 64KB (512 rows x 64 k bf16)

    const int tid = threadIdx.x;
    const int b0  = blockIdx.x;
    // XCD-bijective swizzle, nwg = 1024; bn-pair of one x-panel adjacent
    const int L  = (b0 & 7) * 128 + (b0 >> 3);
    const int bm = L >> 1;            // 512 m-tiles
    const int bn = L & 1;             // 2 n-tiles
    const int m0 = bm * BM;

    const int lane = tid & 63;
    const int wid  = tid >> 6;        // 0..7: wave's 64-col slice of BN=512
    const int arow = tid >> 2;        // 0..127
    const int aseg = tid & 3;         // 0..3 (16-float chunk within BK=64)

    f32x4 acc[8][4] = {};             // 128 AGPR (128x64 wave-tile)
    f32x4 set0[4], set1[4];           // depth-2 A prefetch (named sets)

    auto issueA = [&](int kt, f32x4* s) {
        const float* p = X + (size_t)(m0 + arow) * DK + kt * BK + aseg * 16;
#pragma unroll
        for (int j = 0; j < 4; ++j) s[j] = *(const f32x4*)(p + j * 4);
    };
    auto storeA = [&](const f32x4* s, char* Ab) {
        const int rsw = (arow & 7) << 4;
#pragma unroll
        for (int j = 0; j < 2; ++j) {
            bf16x8 v;
#pragma unroll
            for (int e = 0; e < 4; ++e) { v[e] = (bf16_t)s[j * 2][e]; v[4 + e] = (bf16_t)s[j * 2 + 1][e]; }
            const int kgrp = aseg * 2 + j;
            *(bf16x8*)(Ab + arow * 128 + ((kgrp * 16) ^ rsw)) = v;
        }
    };
    auto issueB = [&](int kt) {
        const char* g = (const char*)WeffSw + (size_t)(bn * 16 + kt) * 65536;
#pragma unroll
        for (int c = 0; c < 8; ++c) {
            const int lin = wid * 8192 + c * 1024;       // wave-uniform dest
            __builtin_amdgcn_global_load_lds(
                (const __attribute__((address_space(1))) void*)(g + lin + lane * 16),
                (__attribute__((address_space(3))) void*)(Blds + lin),
                16, 0, 0);
        }
    };
    auto readBall = [&](bf16x8* bfr) {
#pragma unroll
        for (int ks = 0; ks < 2; ++ks)
#pragma unroll
            for (int nf = 0; nf < 4; ++nf) {
                const int row = wid * 64 + nf * 16 + (lane & 15);
                const int kb  = ks * 64 + (lane >> 4) * 16;
                bfr[ks * 4 + nf] = *(const bf16x8*)(Blds + row * 128 + (kb ^ ((row & 7) << 4)));
            }
    };
    auto computeH = [&](const char* Ac, int ks, int h, const bf16x8* bfr) {
        bf16x8 af[4];
        const int kb = ks * 64 + (lane >> 4) * 16;
#pragma unroll
        for (int i = 0; i < 4; ++i) {
            const int row = (h * 4 + i) * 16 + (lane & 15);
            af[i] = *(const bf16x8*)(Ac + row * 128 + (kb ^ ((row & 7) << 4)));
        }
        __builtin_amdgcn_s_setprio(1);
#pragma unroll
        for (int i = 0; i < 4; ++i)
#pragma unroll
            for (int nf = 0; nf < 4; ++nf)
                acc[h * 4 + i][nf] = __builtin_amdgcn_mfma_f32_16x16x32_bf16(
                    af[i], bfr[nf], acc[h * 4 + i][nf], 0, 0, 0);
        __builtin_amdgcn_s_setprio(0);
    };

    auto iter = [&](int t, const char* Ac, char* An,
                    f32x4* aStore /*holds A(t+1)*/, f32x4* aFill /*gets A(t+2)*/) {
        bf16x8 bfr[8];
        readBall(bfr);                       // B(t) -> regs (32 VGPR)
        asm volatile("s_waitcnt lgkmcnt(0)" ::: "memory");
        __builtin_amdgcn_s_barrier();        // guard: all waves' B-reads done
        if (t + 1 < NKT) issueB(t + 1);      // in-place DMA, lands under MFMAs
        computeH(Ac, 0, 0, bfr);
        computeH(Ac, 0, 1, bfr);
        if (t + 1 < NKT) storeA(aStore, An); // auto-waits aStore globals only
        if (t + 2 < NKT) issueA(t + 2, aFill);
        computeH(Ac, 1, 0, bfr + 4);
        computeH(Ac, 1, 1, bfr + 4);
        if (t + 2 < NKT) {
            asm volatile("s_waitcnt vmcnt(4) lgkmcnt(0)" ::: "memory"); // drain B(t+1), keep A(t+2)
            __builtin_amdgcn_s_barrier();
        } else if (t + 1 < NKT) {
            asm volatile("s_waitcnt vmcnt(0) lgkmcnt(0)" ::: "memory");
            __builtin_amdgcn_s_barrier();
        }
    };

    // ---- prologue: A(0)->LDS, A(1) in regs, B(0) staged ----
    issueA(0, set0);
    issueB(0);
    storeA(set0, Ab0);               // auto-waits A(0) loads (B(0) keeps flying)
    issueA(1, set1);
    asm volatile("s_waitcnt vmcnt(4) lgkmcnt(0)" ::: "memory");  // B(0) done, A(1) flying
    __builtin_amdgcn_s_barrier();

    for (int t = 0; t < NKT; t += 2) {
        iter(t,     Ab0, Ab1, set1, set0);
        iter(t + 1, Ab1, Ab0, set0, set1);
    }
    __syncthreads();                 // LDS free for epilogue reuse

    // ---- epilogue: per-wave LDS transpose -> full-line f32x4 stores --------
    float* tb = (float*)smem + wid * 1280;   // 16 x 80 f32 per wave (40KB)
    const int nbase = bn * BN + wid * 64;
    float bv[4];
#pragma unroll
    for (int nf = 0; nf < 4; ++nf) bv[nf] = bias[nbase + nf * 16 + (lane & 15)];

#pragma unroll
    for (int mf = 0; mf < 8; ++mf) {
#pragma unroll
        for (int nf = 0; nf < 4; ++nf)
#pragma unroll
            for (int j = 0; j < 4; ++j) {
                const int r = (lane >> 4) * 4 + j;
                const int c = nf * 16 + (lane & 15);
                tb[r * 80 + c] = acc[mf][nf][j] + bv[nf];
            }
        __syncthreads();
#pragma unroll
        for (int jj = 0; jj < 4; ++jj) {
            const int rr = jj * 4 + (lane >> 4);
            const int cc = (lane & 15) * 4;
            f32x4 v = *(const f32x4*)&tb[rr * 80 + cc];
            *(f32x4*)&Out[(size_t)(m0 + mf * 16 + rr) * DN + nbase + cc] = v;
        }
        __syncthreads();
    }
}

extern "C" void kernel_launch(void* const* d_in, const int* in_sizes, int n_in,
                              void* d_out, int out_size, void* d_ws, size_t ws_size,
                              hipStream_t stream) {
    const float* x  = (const float*)d_in[0];
    const float* W  = (const float*)d_in[1];
    const float* b  = (const float*)d_in[2];
    const float* Vr = (const float*)d_in[3];
    const float* C  = (const float*)d_in[4];
    float* out = (float*)d_out;

    const int M = in_sizes[0] / DK;            // 65536
    bf16_t* WeffSw = (bf16_t*)d_ws;            // 2 MB pre-swizzled W_eff

    weff_kernel<<<DN, 128, 0, stream>>>(W, Vr, C, WeffSw);

    const int mtiles = M / BM;                 // 512
    const int nwg = mtiles * (DN / BN);        // 1024
    corrlin_gemm_kernel<<<nwg, 512, 0, stream>>>(x, WeffSw, b, out);
}